// Round 17
// baseline (813.780 us; speedup 1.0000x reference)
//
#include <hip/hip_runtime.h>
#include <hip/hip_bf16.h>

#define V_SIZE 32000
#define SEQ 64
#define BATCH 64
#define EMB 32
#define HID 16
#define NROWS (SEQ * BATCH)   // 4096
#define V4 (V_SIZE / 4)       // 8000 float4 columns
#define STRIPS 32             // k_write: 32 strips * 256 f4-cols
#define CHUNKS 64
#define ROWS_W (NROWS / CHUNKS)   // 64 rows per chunk
#define RGROUP 8                  // rows per inner group in k_write
#define NRB (NROWS / 16)          // 256 row-blocks (MFMA M-tiles)
#define NTILES (V_SIZE / 16)      // 2000 col-tiles (MFMA N-tiles)
#define RBW 4                     // row-blocks per wave (b-frag reuse)
#define NRG (NRB / RBW)           // 64 row-groups
#define XSTRIPS 50                // expsum strips
#define TPW (NTILES / XSTRIPS)    // 40 tiles per wave
#define NSLOTS XSTRIPS
#define HT_BLOCKS (NROWS / 256)       // 16
#define WP_BLOCKS (NTILES * 64 / 256) // 500
#define XREPS 16                  // DIAGNOSTIC: expsum tops profile (~350 us)
#define WREPS 4                   // DIAGNOSTIC: write A/B vs R9's 362 us regular-store run

typedef float f32x4 __attribute__((ext_vector_type(4)));
typedef short short8 __attribute__((ext_vector_type(8)));

__device__ inline short bf16_rne(float x) {
    unsigned u = __builtin_bit_cast(unsigned, x);
    unsigned r = u + 0x7FFFu + ((u >> 16) & 1u);
    return (short)(r >> 16);
}

// ---------------------------------------------------------------------------
// Kernel A (merged): blocks 0..15 build h_table + A-frags; blocks 16..515
// pack Wo into bf16 B-frags. Disjoint outputs -> deterministic.
// ---------------------------------------------------------------------------
__global__ __launch_bounds__(256) void k_prep(
    const int* __restrict__ idx, const float* __restrict__ lookup,
    const float* __restrict__ wx, const float* __restrict__ wh,
    const float* __restrict__ h0, const float* __restrict__ wo,
    float* __restrict__ h_table, short* __restrict__ a_frag,
    short* __restrict__ b_frag)
{
    if (blockIdx.x < HT_BLOCKS) {
        int r = blockIdx.x * 256 + threadIdx.x;

        float acc[HID];
        #pragma unroll
        for (int j = 0; j < HID; ++j) acc[j] = 0.f;

        #pragma unroll
        for (int i = 0; i < HID; ++i) {
            float h0i = h0[i];
            #pragma unroll
            for (int j = 0; j < HID; ++j) acc[j] += h0i * wh[i * HID + j];
        }

        int tok = idx[r];
        const float* xrow = lookup + (long)tok * EMB;
        #pragma unroll
        for (int e = 0; e < EMB; ++e) {
            float x = xrow[e];
            #pragma unroll
            for (int j = 0; j < HID; ++j) acc[j] += x * wx[e * HID + j];
        }

        float h[HID];
        #pragma unroll
        for (int j = 0; j < HID; ++j) {
            h[j] = 1.f / (1.f + __expf(-acc[j]));
            h_table[r * HID + j] = h[j];
        }

        const int rb = r >> 4;
        const int m  = r & 15;
        short8 lo, hi, zz;
        #pragma unroll
        for (int j = 0; j < 8; ++j) {
            lo[j] = bf16_rne(h[j]);
            hi[j] = bf16_rne(h[j + 8]);
            zz[j] = 0;
        }
        short8* af = reinterpret_cast<short8*>(a_frag);
        af[rb * 64 + m]      = lo;   // lanes 0..15:  k = 0..7
        af[rb * 64 + m + 16] = hi;   // lanes 16..31: k = 8..15
        af[rb * 64 + m + 32] = zz;   // pad
        af[rb * 64 + m + 48] = zz;   // pad
    } else {
        int gid = (blockIdx.x - HT_BLOCKS) * 256 + threadIdx.x;  // 0..127999
        const int t = gid >> 6;
        const int l = gid & 63;
        const int col = t * 16 + (l & 15);

        short8 b;
        if (l < 32) {
            const int k0 = (l >> 4) * 8;
            #pragma unroll
            for (int j = 0; j < 8; ++j)
                b[j] = bf16_rne(wo[(size_t)(k0 + j) * V_SIZE + col]);
        } else {
            #pragma unroll
            for (int j = 0; j < 8; ++j) b[j] = 0;
        }
        reinterpret_cast<short8*>(b_frag)[gid] = b;
    }
}

// ---------------------------------------------------------------------------
// Kernel B: MFMA exp-sum — RBW=4 + rotation + prefetch-2 (R16 structure).
// XREPS=16 internal repeat (acc reset per rep, identical stores) is
// DIAGNOSTIC ONLY: forces this dispatch into profile top-5 with counters.
// ---------------------------------------------------------------------------
__global__ __launch_bounds__(256) void k_expsum(
    const short* __restrict__ a_frag, const short* __restrict__ b_frag,
    float* __restrict__ partial)
{
    const int lane = threadIdx.x & 63;
    const int wid  = threadIdx.x >> 6;
    const int g = blockIdx.x * 4 + wid;      // 0..3199
    const int rbg = g & (NRG - 1);           // 0..63
    const int strip = g >> 6;                // 0..49

    const short8* af = reinterpret_cast<const short8*>(a_frag);
    const short8* bf = reinterpret_cast<const short8*>(b_frag);

    short8 a[RBW];
    #pragma unroll
    for (int i = 0; i < RBW; ++i)
        a[i] = af[(rbg * RBW + i) * 64 + lane];

    const f32x4 czero = {0.f, 0.f, 0.f, 0.f};
    const int t0 = strip * TPW;
    const int tend = t0 + TPW;
    const int rot = rbg % TPW;

    #pragma unroll 1
    for (int rep = 0; rep < XREPS; ++rep) {
        f32x4 acc[RBW];
        #pragma unroll
        for (int i = 0; i < RBW; ++i) acc[i] = (f32x4){0.f, 0.f, 0.f, 0.f};

        int t  = t0 + rot;
        int tn = t + 1;  if (tn == tend) tn = t0;
        short8 bcur = bf[t * 64 + lane];
        short8 bnxt = bf[tn * 64 + lane];

        for (int i = 0; i < TPW; ++i) {
            int tp = tn + 1;  if (tp == tend) tp = t0;
            short8 bpre = bf[tp * 64 + lane];

            f32x4 d[RBW];
            #pragma unroll
            for (int k = 0; k < RBW; ++k)
                d[k] = __builtin_amdgcn_mfma_f32_16x16x32_bf16(a[k], bcur, czero, 0, 0, 0);

            #pragma unroll
            for (int k = 0; k < RBW; ++k) {
                acc[k].x += __expf(d[k].x);
                acc[k].y += __expf(d[k].y);
                acc[k].z += __expf(d[k].z);
                acc[k].w += __expf(d[k].w);
            }

            bcur = bnxt;
            bnxt = bpre;
            tn = tp;
        }

        // reduce across the 16 column-lanes (lane&15)
        #pragma unroll
        for (int off = 1; off <= 8; off <<= 1) {
            #pragma unroll
            for (int k = 0; k < RBW; ++k) {
                acc[k].x += __shfl_xor(acc[k].x, off, 64);
                acc[k].y += __shfl_xor(acc[k].y, off, 64);
                acc[k].z += __shfl_xor(acc[k].z, off, 64);
                acc[k].w += __shfl_xor(acc[k].w, off, 64);
            }
        }

        if ((lane & 15) == 0) {
            #pragma unroll
            for (int k = 0; k < RBW; ++k) {
                const int rbase = (rbg * RBW + k) * 16 + (lane >> 4) * 4;
                float* p = partial + (size_t)strip * NROWS + rbase;
                p[0] = acc[k].x;
                p[1] = acc[k].y;
                p[2] = acc[k].z;
                p[3] = acc[k].w;
            }
        }
    }
}

// ---------------------------------------------------------------------------
// Kernel C: k_write with fused lse head (R16), NONTEMPORAL stores, WREPS=4
// (A/B vs R9's regular-store REPS=4 = 360-362 us, full counters).
// ---------------------------------------------------------------------------
__global__ __launch_bounds__(256) void k_write(
    const float* __restrict__ h_table, const float* __restrict__ wo,
    const float* __restrict__ partial, float* __restrict__ out)
{
    const int tid = threadIdx.x;
    const int strip = blockIdx.x & (STRIPS - 1);
    const int chunk = blockIdx.x / STRIPS;
    const int v4 = strip * 256 + tid;
    const bool act = v4 < V4;
    const int r0 = chunk * ROWS_W;

    __shared__ float lse_s[ROWS_W];
    if (tid < ROWS_W) {
        float s = 0.f;
        #pragma unroll
        for (int k = 0; k < NSLOTS; ++k)
            s += partial[(size_t)k * NROWS + r0 + tid];
        lse_s[tid] = __logf(s);
    }

    const f32x4* wo4 = reinterpret_cast<const f32x4*>(wo);
    f32x4 w[HID];
    #pragma unroll
    for (int j = 0; j < HID; ++j) {
        if (act) w[j] = wo4[j * V4 + v4];
        else     w[j] = (f32x4){0.f, 0.f, 0.f, 0.f};
    }

    __syncthreads();

    f32x4* out4 = reinterpret_cast<f32x4*>(out);

    #pragma unroll 1
    for (int rep = 0; rep < WREPS; ++rep) {
        for (int rr = r0; rr < r0 + ROWS_W; rr += RGROUP) {
            f32x4 acc[RGROUP];
            #pragma unroll
            for (int i = 0; i < RGROUP; ++i) acc[i] = (f32x4){0.f, 0.f, 0.f, 0.f};

            #pragma unroll
            for (int q = 0; q < 4; ++q) {
                f32x4 h4[RGROUP];
                #pragma unroll
                for (int i = 0; i < RGROUP; ++i)
                    h4[i] = *reinterpret_cast<const f32x4*>(h_table + (rr + i) * HID + q * 4);
                #pragma unroll
                for (int i = 0; i < RGROUP; ++i) {
                    acc[i] += h4[i].x * w[q * 4 + 0];
                    acc[i] += h4[i].y * w[q * 4 + 1];
                    acc[i] += h4[i].z * w[q * 4 + 2];
                    acc[i] += h4[i].w * w[q * 4 + 3];
                }
            }

            if (act) {
                #pragma unroll
                for (int i = 0; i < RGROUP; ++i) {
                    float l = lse_s[rr - r0 + i];
                    f32x4 o = acc[i] - l;
                    __builtin_nontemporal_store(o, &out4[(long)(rr + i) * V4 + v4]);
                }
            }
        }
    }
}

extern "C" void kernel_launch(void* const* d_in, const int* in_sizes, int n_in,
                              void* d_out, int out_size, void* d_ws, size_t ws_size,
                              hipStream_t stream) {
    const int*   idx    = (const int*)d_in[0];
    const float* lookup = (const float*)d_in[1];
    const float* wx     = (const float*)d_in[2];
    const float* wh     = (const float*)d_in[3];
    const float* wo     = (const float*)d_in[4];
    const float* h0     = (const float*)d_in[5];
    float* out = (float*)d_out;

    float* h_table = (float*)d_ws;                       // 4096*16 f32   (256 KB)
    float* partial = h_table + NROWS * HID;              // 50*4096 f32   (800 KB)
    short* a_frag  = (short*)(partial + NSLOTS * NROWS); // 256*64*8 bf16 (256 KB)
    short* b_frag  = a_frag + NRB * 64 * 8;              // 2000*64*8 bf16 (2 MB)

    k_prep<<<HT_BLOCKS + WP_BLOCKS, 256, 0, stream>>>(idx, lookup, wx, wh, h0, wo,
                                                      h_table, a_frag, b_frag);
    k_expsum<<<(NRG * XSTRIPS) / 4, 256, 0, stream>>>(a_frag, b_frag, partial);
    k_write<<<STRIPS * CHUNKS, 256, 0, stream>>>(h_table, wo, partial, out);
}

// Round 18
// 165.835 us; speedup vs baseline: 4.9072x; 4.9072x over previous
//
#include <hip/hip_runtime.h>
#include <hip/hip_bf16.h>

#define V_SIZE 32000
#define SEQ 64
#define BATCH 64
#define EMB 32
#define HID 16
#define NROWS (SEQ * BATCH)   // 4096
#define V4 (V_SIZE / 4)       // 8000 float4 columns
#define STRIPS 32             // k_write: 32 strips * 256 f4-cols
#define CHUNKS 64
#define ROWS_W (NROWS / CHUNKS)   // 64 rows per chunk
#define RGROUP 8                  // rows per inner group in k_write
#define NRB (NROWS / 16)          // 256 row-blocks (MFMA M-tiles)
#define NTILES (V_SIZE / 16)      // 2000 col-tiles (MFMA N-tiles)
#define RBW 4                     // row-blocks per wave (b-frag reuse)
#define NRG (NRB / RBW)           // 64 row-groups
#define XSTRIPS 100               // expsum strips (6400 waves = 25/CU)
#define TPW (NTILES / XSTRIPS)    // 20 tiles per wave
#define NSLOTS XSTRIPS
#define HT_BLOCKS (NROWS / 256)       // 16
#define WP_BLOCKS (NTILES * 64 / 256) // 500

#define LOG2E 1.4426950408889634f

typedef float f32x4 __attribute__((ext_vector_type(4)));
typedef short short8 __attribute__((ext_vector_type(8)));

__device__ inline short bf16_rne(float x) {
    unsigned u = __builtin_bit_cast(unsigned, x);
    unsigned r = u + 0x7FFFu + ((u >> 16) & 1u);
    return (short)(r >> 16);
}

// ---------------------------------------------------------------------------
// Kernel A (merged): blocks 0..15 build h_table + A-frags; blocks 16..515
// pack Wo into bf16 B-frags. A-frags are PRE-SCALED by log2(e) so expsum's
// MFMA outputs d = log2e*logit and exp(logit) = exp2(d) = single v_exp_f32
// (saves the per-exp v_mul). Disjoint outputs -> deterministic.
// ---------------------------------------------------------------------------
__global__ __launch_bounds__(256) void k_prep(
    const int* __restrict__ idx, const float* __restrict__ lookup,
    const float* __restrict__ wx, const float* __restrict__ wh,
    const float* __restrict__ h0, const float* __restrict__ wo,
    float* __restrict__ h_table, short* __restrict__ a_frag,
    short* __restrict__ b_frag)
{
    if (blockIdx.x < HT_BLOCKS) {
        int r = blockIdx.x * 256 + threadIdx.x;

        float acc[HID];
        #pragma unroll
        for (int j = 0; j < HID; ++j) acc[j] = 0.f;

        #pragma unroll
        for (int i = 0; i < HID; ++i) {
            float h0i = h0[i];
            #pragma unroll
            for (int j = 0; j < HID; ++j) acc[j] += h0i * wh[i * HID + j];
        }

        int tok = idx[r];
        const float* xrow = lookup + (long)tok * EMB;
        #pragma unroll
        for (int e = 0; e < EMB; ++e) {
            float x = xrow[e];
            #pragma unroll
            for (int j = 0; j < HID; ++j) acc[j] += x * wx[e * HID + j];
        }

        float h[HID];
        #pragma unroll
        for (int j = 0; j < HID; ++j) {
            h[j] = 1.f / (1.f + __expf(-acc[j]));
            h_table[r * HID + j] = h[j];
        }

        const int rb = r >> 4;
        const int m  = r & 15;
        short8 lo, hi, zz;
        #pragma unroll
        for (int j = 0; j < 8; ++j) {
            lo[j] = bf16_rne(h[j] * LOG2E);       // pre-scaled by log2(e)
            hi[j] = bf16_rne(h[j + 8] * LOG2E);
            zz[j] = 0;
        }
        short8* af = reinterpret_cast<short8*>(a_frag);
        af[rb * 64 + m]      = lo;   // lanes 0..15:  k = 0..7
        af[rb * 64 + m + 16] = hi;   // lanes 16..31: k = 8..15
        af[rb * 64 + m + 32] = zz;   // pad
        af[rb * 64 + m + 48] = zz;   // pad
    } else {
        int gid = (blockIdx.x - HT_BLOCKS) * 256 + threadIdx.x;  // 0..127999
        const int t = gid >> 6;
        const int l = gid & 63;
        const int col = t * 16 + (l & 15);

        short8 b;
        if (l < 32) {
            const int k0 = (l >> 4) * 8;
            #pragma unroll
            for (int j = 0; j < 8; ++j)
                b[j] = bf16_rne(wo[(size_t)(k0 + j) * V_SIZE + col]);
        } else {
            #pragma unroll
            for (int j = 0; j < 8; ++j) b[j] = 0;
        }
        reinterpret_cast<short8*>(b_frag)[gid] = b;
    }
}

// ---------------------------------------------------------------------------
// Kernel B: MFMA exp-sum. RBW=4 + rotation + prefetch-2; 6400 waves (25/CU,
// counters showed 12.5/CU capped VALUBusy at 70%); exp2f single-instruction
// exponentials (A pre-scaled by log2e).
// C/D layout (m89-verified): col=lane&15, row=(lane>>4)*4+reg.
// ---------------------------------------------------------------------------
__global__ __launch_bounds__(256) void k_expsum(
    const short* __restrict__ a_frag, const short* __restrict__ b_frag,
    float* __restrict__ partial)
{
    const int lane = threadIdx.x & 63;
    const int wid  = threadIdx.x >> 6;
    const int g = blockIdx.x * 4 + wid;      // 0..6399
    const int rbg = g & (NRG - 1);           // 0..63
    const int strip = g >> 6;                // 0..99

    const short8* af = reinterpret_cast<const short8*>(a_frag);
    const short8* bf = reinterpret_cast<const short8*>(b_frag);

    short8 a[RBW];
    #pragma unroll
    for (int i = 0; i < RBW; ++i)
        a[i] = af[(rbg * RBW + i) * 64 + lane];

    const f32x4 czero = {0.f, 0.f, 0.f, 0.f};
    const int t0 = strip * TPW;
    const int tend = t0 + TPW;
    const int rot = rbg % TPW;

    f32x4 acc[RBW];
    #pragma unroll
    for (int i = 0; i < RBW; ++i) acc[i] = (f32x4){0.f, 0.f, 0.f, 0.f};

    int t  = t0 + rot;
    int tn = t + 1;  if (tn == tend) tn = t0;
    short8 bcur = bf[t * 64 + lane];
    short8 bnxt = bf[tn * 64 + lane];

    for (int i = 0; i < TPW; ++i) {
        int tp = tn + 1;  if (tp == tend) tp = t0;
        short8 bpre = bf[tp * 64 + lane];

        f32x4 d[RBW];
        #pragma unroll
        for (int k = 0; k < RBW; ++k)
            d[k] = __builtin_amdgcn_mfma_f32_16x16x32_bf16(a[k], bcur, czero, 0, 0, 0);

        #pragma unroll
        for (int k = 0; k < RBW; ++k) {
            acc[k].x += exp2f(d[k].x);
            acc[k].y += exp2f(d[k].y);
            acc[k].z += exp2f(d[k].z);
            acc[k].w += exp2f(d[k].w);
        }

        bcur = bnxt;
        bnxt = bpre;
        tn = tp;
    }

    // reduce across the 16 column-lanes (lane&15)
    #pragma unroll
    for (int off = 1; off <= 8; off <<= 1) {
        #pragma unroll
        for (int k = 0; k < RBW; ++k) {
            acc[k].x += __shfl_xor(acc[k].x, off, 64);
            acc[k].y += __shfl_xor(acc[k].y, off, 64);
            acc[k].z += __shfl_xor(acc[k].z, off, 64);
            acc[k].w += __shfl_xor(acc[k].w, off, 64);
        }
    }

    if ((lane & 15) == 0) {
        #pragma unroll
        for (int k = 0; k < RBW; ++k) {
            const int rbase = (rbg * RBW + k) * 16 + (lane >> 4) * 4;
            float* p = partial + (size_t)strip * NROWS + rbase;
            p[0] = acc[k].x;
            p[1] = acc[k].y;
            p[2] = acc[k].z;
            p[3] = acc[k].w;
        }
    }
}

// ---------------------------------------------------------------------------
// Kernel C: k_write with fused lse head (100 slots), regular stores
// (R17 A/B: NT == regular within noise). Body = R9 structure (~90 us).
// ---------------------------------------------------------------------------
__global__ __launch_bounds__(256) void k_write(
    const float* __restrict__ h_table, const float* __restrict__ wo,
    const float* __restrict__ partial, float* __restrict__ out)
{
    const int tid = threadIdx.x;
    const int strip = blockIdx.x & (STRIPS - 1);
    const int chunk = blockIdx.x / STRIPS;
    const int v4 = strip * 256 + tid;
    const bool act = v4 < V4;
    const int r0 = chunk * ROWS_W;

    __shared__ float lse_s[ROWS_W];
    if (tid < ROWS_W) {
        float s = 0.f;
        #pragma unroll
        for (int k = 0; k < NSLOTS; ++k)
            s += partial[(size_t)k * NROWS + r0 + tid];
        lse_s[tid] = __logf(s);
    }

    const f32x4* wo4 = reinterpret_cast<const f32x4*>(wo);
    f32x4 w[HID];
    #pragma unroll
    for (int j = 0; j < HID; ++j) {
        if (act) w[j] = wo4[j * V4 + v4];
        else     w[j] = (f32x4){0.f, 0.f, 0.f, 0.f};
    }

    __syncthreads();

    f32x4* out4 = reinterpret_cast<f32x4*>(out);

    for (int rr = r0; rr < r0 + ROWS_W; rr += RGROUP) {
        f32x4 acc[RGROUP];
        #pragma unroll
        for (int i = 0; i < RGROUP; ++i) acc[i] = (f32x4){0.f, 0.f, 0.f, 0.f};

        #pragma unroll
        for (int q = 0; q < 4; ++q) {
            f32x4 h4[RGROUP];
            #pragma unroll
            for (int i = 0; i < RGROUP; ++i)
                h4[i] = *reinterpret_cast<const f32x4*>(h_table + (rr + i) * HID + q * 4);
            #pragma unroll
            for (int i = 0; i < RGROUP; ++i) {
                acc[i] += h4[i].x * w[q * 4 + 0];
                acc[i] += h4[i].y * w[q * 4 + 1];
                acc[i] += h4[i].z * w[q * 4 + 2];
                acc[i] += h4[i].w * w[q * 4 + 3];
            }
        }

        if (act) {
            #pragma unroll
            for (int i = 0; i < RGROUP; ++i) {
                float l = lse_s[rr - r0 + i];
                f32x4 o = acc[i] - l;
                out4[(long)(rr + i) * V4 + v4] = o;
            }
        }
    }
}

extern "C" void kernel_launch(void* const* d_in, const int* in_sizes, int n_in,
                              void* d_out, int out_size, void* d_ws, size_t ws_size,
                              hipStream_t stream) {
    const int*   idx    = (const int*)d_in[0];
    const float* lookup = (const float*)d_in[1];
    const float* wx     = (const float*)d_in[2];
    const float* wh     = (const float*)d_in[3];
    const float* wo     = (const float*)d_in[4];
    const float* h0     = (const float*)d_in[5];
    float* out = (float*)d_out;

    float* h_table = (float*)d_ws;                       // 4096*16 f32   (256 KB)
    float* partial = h_table + NROWS * HID;              // 100*4096 f32  (1.6 MB)
    short* a_frag  = (short*)(partial + NSLOTS * NROWS); // 256*64*8 bf16 (256 KB)
    short* b_frag  = a_frag + NRB * 64 * 8;              // 2000*64*8 bf16 (2 MB)

    k_prep<<<HT_BLOCKS + WP_BLOCKS, 256, 0, stream>>>(idx, lookup, wx, wh, h0, wo,
                                                      h_table, a_frag, b_frag);
    k_expsum<<<(NRG * XSTRIPS) / 4, 256, 0, stream>>>(a_frag, b_frag, partial);
    k_write<<<STRIPS * CHUNKS, 256, 0, stream>>>(h_table, wo, partial, out);
}

// Round 19
// 164.290 us; speedup vs baseline: 4.9533x; 1.0094x over previous
//
#include <hip/hip_runtime.h>
#include <hip/hip_bf16.h>

#define V_SIZE 32000
#define SEQ 64
#define BATCH 64
#define EMB 32
#define HID 16
#define NROWS (SEQ * BATCH)   // 4096
#define V4 (V_SIZE / 4)       // 8000 float4 columns
#define STRIPS 32             // k_write: 32 strips * 256 f4-cols
#define CHUNKS 32             // <- single change vs R16 (was 64): ROWS_W 64->128
#define ROWS_W (NROWS / CHUNKS)   // 128 rows per chunk
#define RGROUP 8                  // rows per inner group in k_write
#define NRB (NROWS / 16)          // 256 row-blocks (MFMA M-tiles)
#define NTILES (V_SIZE / 16)      // 2000 col-tiles (MFMA N-tiles)
#define RBW 4                     // row-blocks per wave (b-frag reuse)
#define NRG (NRB / RBW)           // 64 row-groups
#define XSTRIPS 50                // expsum strips (R16 config)
#define TPW (NTILES / XSTRIPS)    // 40 tiles per wave
#define NSLOTS XSTRIPS
#define HT_BLOCKS (NROWS / 256)       // 16
#define WP_BLOCKS (NTILES * 64 / 256) // 500

typedef float f32x4 __attribute__((ext_vector_type(4)));
typedef short short8 __attribute__((ext_vector_type(8)));

__device__ inline short bf16_rne(float x) {
    unsigned u = __builtin_bit_cast(unsigned, x);
    unsigned r = u + 0x7FFFu + ((u >> 16) & 1u);
    return (short)(r >> 16);
}

// ---------------------------------------------------------------------------
// Kernel A (merged): blocks 0..15 build h_table + A-frags; blocks 16..515
// pack Wo into bf16 B-frags. Disjoint outputs -> deterministic. (R16 exact.)
// ---------------------------------------------------------------------------
__global__ __launch_bounds__(256) void k_prep(
    const int* __restrict__ idx, const float* __restrict__ lookup,
    const float* __restrict__ wx, const float* __restrict__ wh,
    const float* __restrict__ h0, const float* __restrict__ wo,
    float* __restrict__ h_table, short* __restrict__ a_frag,
    short* __restrict__ b_frag)
{
    if (blockIdx.x < HT_BLOCKS) {
        int r = blockIdx.x * 256 + threadIdx.x;

        float acc[HID];
        #pragma unroll
        for (int j = 0; j < HID; ++j) acc[j] = 0.f;

        #pragma unroll
        for (int i = 0; i < HID; ++i) {
            float h0i = h0[i];
            #pragma unroll
            for (int j = 0; j < HID; ++j) acc[j] += h0i * wh[i * HID + j];
        }

        int tok = idx[r];
        const float* xrow = lookup + (long)tok * EMB;
        #pragma unroll
        for (int e = 0; e < EMB; ++e) {
            float x = xrow[e];
            #pragma unroll
            for (int j = 0; j < HID; ++j) acc[j] += x * wx[e * HID + j];
        }

        float h[HID];
        #pragma unroll
        for (int j = 0; j < HID; ++j) {
            h[j] = 1.f / (1.f + __expf(-acc[j]));
            h_table[r * HID + j] = h[j];
        }

        const int rb = r >> 4;
        const int m  = r & 15;
        short8 lo, hi, zz;
        #pragma unroll
        for (int j = 0; j < 8; ++j) {
            lo[j] = bf16_rne(h[j]);
            hi[j] = bf16_rne(h[j + 8]);
            zz[j] = 0;
        }
        short8* af = reinterpret_cast<short8*>(a_frag);
        af[rb * 64 + m]      = lo;   // lanes 0..15:  k = 0..7
        af[rb * 64 + m + 16] = hi;   // lanes 16..31: k = 8..15
        af[rb * 64 + m + 32] = zz;   // pad
        af[rb * 64 + m + 48] = zz;   // pad
    } else {
        int gid = (blockIdx.x - HT_BLOCKS) * 256 + threadIdx.x;  // 0..127999
        const int t = gid >> 6;
        const int l = gid & 63;
        const int col = t * 16 + (l & 15);

        short8 b;
        if (l < 32) {
            const int k0 = (l >> 4) * 8;
            #pragma unroll
            for (int j = 0; j < 8; ++j)
                b[j] = bf16_rne(wo[(size_t)(k0 + j) * V_SIZE + col]);
        } else {
            #pragma unroll
            for (int j = 0; j < 8; ++j) b[j] = 0;
        }
        reinterpret_cast<short8*>(b_frag)[gid] = b;
    }
}

// ---------------------------------------------------------------------------
// Kernel B: MFMA exp-sum — RBW=4 + rotation + prefetch-2 (R16 exact).
// C/D layout (m89-verified): col=lane&15, row=(lane>>4)*4+reg.
// ---------------------------------------------------------------------------
__global__ __launch_bounds__(256) void k_expsum(
    const short* __restrict__ a_frag, const short* __restrict__ b_frag,
    float* __restrict__ partial)
{
    const int lane = threadIdx.x & 63;
    const int wid  = threadIdx.x >> 6;
    const int g = blockIdx.x * 4 + wid;      // 0..3199
    const int rbg = g & (NRG - 1);           // 0..63
    const int strip = g >> 6;                // 0..49

    const short8* af = reinterpret_cast<const short8*>(a_frag);
    const short8* bf = reinterpret_cast<const short8*>(b_frag);

    short8 a[RBW];
    #pragma unroll
    for (int i = 0; i < RBW; ++i)
        a[i] = af[(rbg * RBW + i) * 64 + lane];

    const f32x4 czero = {0.f, 0.f, 0.f, 0.f};
    const int t0 = strip * TPW;
    const int tend = t0 + TPW;
    const int rot = rbg % TPW;

    f32x4 acc[RBW];
    #pragma unroll
    for (int i = 0; i < RBW; ++i) acc[i] = (f32x4){0.f, 0.f, 0.f, 0.f};

    int t  = t0 + rot;
    int tn = t + 1;  if (tn == tend) tn = t0;
    short8 bcur = bf[t * 64 + lane];
    short8 bnxt = bf[tn * 64 + lane];

    for (int i = 0; i < TPW; ++i) {
        int tp = tn + 1;  if (tp == tend) tp = t0;
        short8 bpre = bf[tp * 64 + lane];

        f32x4 d[RBW];
        #pragma unroll
        for (int k = 0; k < RBW; ++k)
            d[k] = __builtin_amdgcn_mfma_f32_16x16x32_bf16(a[k], bcur, czero, 0, 0, 0);

        #pragma unroll
        for (int k = 0; k < RBW; ++k) {
            acc[k].x += __expf(d[k].x);
            acc[k].y += __expf(d[k].y);
            acc[k].z += __expf(d[k].z);
            acc[k].w += __expf(d[k].w);
        }

        bcur = bnxt;
        bnxt = bpre;
        tn = tp;
    }

    // reduce across the 16 column-lanes (lane&15)
    #pragma unroll
    for (int off = 1; off <= 8; off <<= 1) {
        #pragma unroll
        for (int k = 0; k < RBW; ++k) {
            acc[k].x += __shfl_xor(acc[k].x, off, 64);
            acc[k].y += __shfl_xor(acc[k].y, off, 64);
            acc[k].z += __shfl_xor(acc[k].z, off, 64);
            acc[k].w += __shfl_xor(acc[k].w, off, 64);
        }
    }

    if ((lane & 15) == 0) {
        #pragma unroll
        for (int k = 0; k < RBW; ++k) {
            const int rbase = (rbg * RBW + k) * 16 + (lane >> 4) * 4;
            float* p = partial + (size_t)strip * NROWS + rbase;
            p[0] = acc[k].x;
            p[1] = acc[k].y;
            p[2] = acc[k].z;
            p[3] = acc[k].w;
        }
    }
}

// ---------------------------------------------------------------------------
// Kernel C: k_write with fused lse head (50 slots), regular stores, R9 body.
// Single change vs R16: CHUNKS 64->32 (ROWS_W=128) — halves block count,
// Wo register-load traffic (64->32 MB) and lse-head reads; same occupancy.
// ---------------------------------------------------------------------------
__global__ __launch_bounds__(256) void k_write(
    const float* __restrict__ h_table, const float* __restrict__ wo,
    const float* __restrict__ partial, float* __restrict__ out)
{
    const int tid = threadIdx.x;
    const int strip = blockIdx.x & (STRIPS - 1);
    const int chunk = blockIdx.x / STRIPS;
    const int v4 = strip * 256 + tid;
    const bool act = v4 < V4;
    const int r0 = chunk * ROWS_W;

    __shared__ float lse_s[ROWS_W];
    if (tid < ROWS_W) {
        float s = 0.f;
        #pragma unroll
        for (int k = 0; k < NSLOTS; ++k)
            s += partial[(size_t)k * NROWS + r0 + tid];
        lse_s[tid] = __logf(s);
    }

    const f32x4* wo4 = reinterpret_cast<const f32x4*>(wo);
    f32x4 w[HID];
    #pragma unroll
    for (int j = 0; j < HID; ++j) {
        if (act) w[j] = wo4[j * V4 + v4];
        else     w[j] = (f32x4){0.f, 0.f, 0.f, 0.f};
    }

    __syncthreads();

    f32x4* out4 = reinterpret_cast<f32x4*>(out);

    for (int rr = r0; rr < r0 + ROWS_W; rr += RGROUP) {
        f32x4 acc[RGROUP];
        #pragma unroll
        for (int i = 0; i < RGROUP; ++i) acc[i] = (f32x4){0.f, 0.f, 0.f, 0.f};

        #pragma unroll
        for (int q = 0; q < 4; ++q) {
            f32x4 h4[RGROUP];
            #pragma unroll
            for (int i = 0; i < RGROUP; ++i)
                h4[i] = *reinterpret_cast<const f32x4*>(h_table + (rr + i) * HID + q * 4);
            #pragma unroll
            for (int i = 0; i < RGROUP; ++i) {
                acc[i] += h4[i].x * w[q * 4 + 0];
                acc[i] += h4[i].y * w[q * 4 + 1];
                acc[i] += h4[i].z * w[q * 4 + 2];
                acc[i] += h4[i].w * w[q * 4 + 3];
            }
        }

        if (act) {
            #pragma unroll
            for (int i = 0; i < RGROUP; ++i) {
                float l = lse_s[rr - r0 + i];
                f32x4 o = acc[i] - l;
                out4[(long)(rr + i) * V4 + v4] = o;
            }
        }
    }
}

extern "C" void kernel_launch(void* const* d_in, const int* in_sizes, int n_in,
                              void* d_out, int out_size, void* d_ws, size_t ws_size,
                              hipStream_t stream) {
    const int*   idx    = (const int*)d_in[0];
    const float* lookup = (const float*)d_in[1];
    const float* wx     = (const float*)d_in[2];
    const float* wh     = (const float*)d_in[3];
    const float* wo     = (const float*)d_in[4];
    const float* h0     = (const float*)d_in[5];
    float* out = (float*)d_out;

    float* h_table = (float*)d_ws;                       // 4096*16 f32   (256 KB)
    float* partial = h_table + NROWS * HID;              // 50*4096 f32   (800 KB)
    short* a_frag  = (short*)(partial + NSLOTS * NROWS); // 256*64*8 bf16 (256 KB)
    short* b_frag  = a_frag + NRB * 64 * 8;              // 2000*64*8 bf16 (2 MB)

    k_prep<<<HT_BLOCKS + WP_BLOCKS, 256, 0, stream>>>(idx, lookup, wx, wh, h0, wo,
                                                      h_table, a_frag, b_frag);
    k_expsum<<<(NRG * XSTRIPS) / 4, 256, 0, stream>>>(a_frag, b_frag, partial);
    k_write<<<STRIPS * CHUNKS, 256, 0, stream>>>(h_table, wo, partial, out);
}

// Round 21
// 159.591 us; speedup vs baseline: 5.0992x; 1.0294x over previous
//
#include <hip/hip_runtime.h>
#include <hip/hip_bf16.h>

#define V_SIZE 32000
#define SEQ 64
#define BATCH 64
#define EMB 32
#define HID 16
#define NROWS (SEQ * BATCH)   // 4096
#define V4 (V_SIZE / 4)       // 8000 float4 columns
#define STRIPS 32             // k_write: 32 strips * 256 f4-cols
#define CHUNKS 64
#define ROWS_W (NROWS / CHUNKS)   // 64 rows per chunk
#define RGROUP 8                  // rows per inner group in k_write
#define NRB (NROWS / 16)          // 256 row-blocks (MFMA M-tiles)
#define NTILES (V_SIZE / 16)      // 2000 col-tiles (MFMA N-tiles)
#define RBW 4                     // row-blocks per wave (b-frag reuse)
#define NRG (NRB / RBW)           // 64 row-groups
#define XSTRIPS 50                // expsum strips
#define TPW (NTILES / XSTRIPS)    // 40 tiles per wave
#define NSLOTS XSTRIPS
#define HT_BLOCKS (NROWS / 256)       // 16
#define WP_BLOCKS (NTILES * 64 / 256) // 500

typedef float f32x4 __attribute__((ext_vector_type(4)));
typedef short short8 __attribute__((ext_vector_type(8)));

__device__ inline short bf16_rne(float x) {
    unsigned u = __builtin_bit_cast(unsigned, x);
    unsigned r = u + 0x7FFFu + ((u >> 16) & 1u);
    return (short)(r >> 16);
}

// ---------------------------------------------------------------------------
// Kernel A (merged): blocks 0..15 build h_table + A-frags; blocks 16..515
// pack Wo into bf16 B-frags. Disjoint outputs -> deterministic. (R16 exact.)
// ---------------------------------------------------------------------------
__global__ __launch_bounds__(256) void k_prep(
    const int* __restrict__ idx, const float* __restrict__ lookup,
    const float* __restrict__ wx, const float* __restrict__ wh,
    const float* __restrict__ h0, const float* __restrict__ wo,
    float* __restrict__ h_table, short* __restrict__ a_frag,
    short* __restrict__ b_frag)
{
    if (blockIdx.x < HT_BLOCKS) {
        int r = blockIdx.x * 256 + threadIdx.x;

        float acc[HID];
        #pragma unroll
        for (int j = 0; j < HID; ++j) acc[j] = 0.f;

        #pragma unroll
        for (int i = 0; i < HID; ++i) {
            float h0i = h0[i];
            #pragma unroll
            for (int j = 0; j < HID; ++j) acc[j] += h0i * wh[i * HID + j];
        }

        int tok = idx[r];
        const float* xrow = lookup + (long)tok * EMB;
        #pragma unroll
        for (int e = 0; e < EMB; ++e) {
            float x = xrow[e];
            #pragma unroll
            for (int j = 0; j < HID; ++j) acc[j] += x * wx[e * HID + j];
        }

        float h[HID];
        #pragma unroll
        for (int j = 0; j < HID; ++j) {
            h[j] = 1.f / (1.f + __expf(-acc[j]));
            h_table[r * HID + j] = h[j];
        }

        const int rb = r >> 4;
        const int m  = r & 15;
        short8 lo, hi, zz;
        #pragma unroll
        for (int j = 0; j < 8; ++j) {
            lo[j] = bf16_rne(h[j]);
            hi[j] = bf16_rne(h[j + 8]);
            zz[j] = 0;
        }
        short8* af = reinterpret_cast<short8*>(a_frag);
        af[rb * 64 + m]      = lo;   // lanes 0..15:  k = 0..7
        af[rb * 64 + m + 16] = hi;   // lanes 16..31: k = 8..15
        af[rb * 64 + m + 32] = zz;   // pad
        af[rb * 64 + m + 48] = zz;   // pad
    } else {
        int gid = (blockIdx.x - HT_BLOCKS) * 256 + threadIdx.x;  // 0..127999
        const int t = gid >> 6;
        const int l = gid & 63;
        const int col = t * 16 + (l & 15);

        short8 b;
        if (l < 32) {
            const int k0 = (l >> 4) * 8;
            #pragma unroll
            for (int j = 0; j < 8; ++j)
                b[j] = bf16_rne(wo[(size_t)(k0 + j) * V_SIZE + col]);
        } else {
            #pragma unroll
            for (int j = 0; j < 8; ++j) b[j] = 0;
        }
        reinterpret_cast<short8*>(b_frag)[gid] = b;
    }
}

// ---------------------------------------------------------------------------
// Kernel B: MFMA exp-sum — RBW=4 + rotation + prefetch-2 (R16 exact).
// C/D layout (m89-verified): col=lane&15, row=(lane>>4)*4+reg.
// ---------------------------------------------------------------------------
__global__ __launch_bounds__(256) void k_expsum(
    const short* __restrict__ a_frag, const short* __restrict__ b_frag,
    float* __restrict__ partial)
{
    const int lane = threadIdx.x & 63;
    const int wid  = threadIdx.x >> 6;
    const int g = blockIdx.x * 4 + wid;      // 0..3199
    const int rbg = g & (NRG - 1);           // 0..63
    const int strip = g >> 6;                // 0..49

    const short8* af = reinterpret_cast<const short8*>(a_frag);
    const short8* bf = reinterpret_cast<const short8*>(b_frag);

    short8 a[RBW];
    #pragma unroll
    for (int i = 0; i < RBW; ++i)
        a[i] = af[(rbg * RBW + i) * 64 + lane];

    const f32x4 czero = {0.f, 0.f, 0.f, 0.f};
    const int t0 = strip * TPW;
    const int tend = t0 + TPW;
    const int rot = rbg % TPW;

    f32x4 acc[RBW];
    #pragma unroll
    for (int i = 0; i < RBW; ++i) acc[i] = (f32x4){0.f, 0.f, 0.f, 0.f};

    int t  = t0 + rot;
    int tn = t + 1;  if (tn == tend) tn = t0;
    short8 bcur = bf[t * 64 + lane];
    short8 bnxt = bf[tn * 64 + lane];

    for (int i = 0; i < TPW; ++i) {
        int tp = tn + 1;  if (tp == tend) tp = t0;
        short8 bpre = bf[tp * 64 + lane];

        f32x4 d[RBW];
        #pragma unroll
        for (int k = 0; k < RBW; ++k)
            d[k] = __builtin_amdgcn_mfma_f32_16x16x32_bf16(a[k], bcur, czero, 0, 0, 0);

        #pragma unroll
        for (int k = 0; k < RBW; ++k) {
            acc[k].x += __expf(d[k].x);
            acc[k].y += __expf(d[k].y);
            acc[k].z += __expf(d[k].z);
            acc[k].w += __expf(d[k].w);
        }

        bcur = bnxt;
        bnxt = bpre;
        tn = tp;
    }

    // reduce across the 16 column-lanes (lane&15)
    #pragma unroll
    for (int off = 1; off <= 8; off <<= 1) {
        #pragma unroll
        for (int k = 0; k < RBW; ++k) {
            acc[k].x += __shfl_xor(acc[k].x, off, 64);
            acc[k].y += __shfl_xor(acc[k].y, off, 64);
            acc[k].z += __shfl_xor(acc[k].z, off, 64);
            acc[k].w += __shfl_xor(acc[k].w, off, 64);
        }
    }

    if ((lane & 15) == 0) {
        #pragma unroll
        for (int k = 0; k < RBW; ++k) {
            const int rbase = (rbg * RBW + k) * 16 + (lane >> 4) * 4;
            float* p = partial + (size_t)strip * NROWS + rbase;
            p[0] = acc[k].x;
            p[1] = acc[k].y;
            p[2] = acc[k].z;
            p[3] = acc[k].w;
        }
    }
}

// ---------------------------------------------------------------------------
// Kernel C: k_write with fused lse head (50 slots), regular stores, R9 body,
// CHUNKS=64. (R16 exact — measured best: 157.9 us total.)
// ---------------------------------------------------------------------------
__global__ __launch_bounds__(256) void k_write(
    const float* __restrict__ h_table, const float* __restrict__ wo,
    const float* __restrict__ partial, float* __restrict__ out)
{
    const int tid = threadIdx.x;
    const int strip = blockIdx.x & (STRIPS - 1);
    const int chunk = blockIdx.x / STRIPS;
    const int v4 = strip * 256 + tid;
    const bool act = v4 < V4;
    const int r0 = chunk * ROWS_W;

    __shared__ float lse_s[ROWS_W];
    if (tid < ROWS_W) {
        float s = 0.f;
        #pragma unroll
        for (int k = 0; k < NSLOTS; ++k)
            s += partial[(size_t)k * NROWS + r0 + tid];
        lse_s[tid] = __logf(s);
    }

    const f32x4* wo4 = reinterpret_cast<const f32x4*>(wo);
    f32x4 w[HID];
    #pragma unroll
    for (int j = 0; j < HID; ++j) {
        if (act) w[j] = wo4[j * V4 + v4];
        else     w[j] = (f32x4){0.f, 0.f, 0.f, 0.f};
    }

    __syncthreads();

    f32x4* out4 = reinterpret_cast<f32x4*>(out);

    for (int rr = r0; rr < r0 + ROWS_W; rr += RGROUP) {
        f32x4 acc[RGROUP];
        #pragma unroll
        for (int i = 0; i < RGROUP; ++i) acc[i] = (f32x4){0.f, 0.f, 0.f, 0.f};

        #pragma unroll
        for (int q = 0; q < 4; ++q) {
            f32x4 h4[RGROUP];
            #pragma unroll
            for (int i = 0; i < RGROUP; ++i)
                h4[i] = *reinterpret_cast<const f32x4*>(h_table + (rr + i) * HID + q * 4);
            #pragma unroll
            for (int i = 0; i < RGROUP; ++i) {
                acc[i] += h4[i].x * w[q * 4 + 0];
                acc[i] += h4[i].y * w[q * 4 + 1];
                acc[i] += h4[i].z * w[q * 4 + 2];
                acc[i] += h4[i].w * w[q * 4 + 3];
            }
        }

        if (act) {
            #pragma unroll
            for (int i = 0; i < RGROUP; ++i) {
                float l = lse_s[rr - r0 + i];
                f32x4 o = acc[i] - l;
                out4[(long)(rr + i) * V4 + v4] = o;
            }
        }
    }
}

extern "C" void kernel_launch(void* const* d_in, const int* in_sizes, int n_in,
                              void* d_out, int out_size, void* d_ws, size_t ws_size,
                              hipStream_t stream) {
    const int*   idx    = (const int*)d_in[0];
    const float* lookup = (const float*)d_in[1];
    const float* wx     = (const float*)d_in[2];
    const float* wh     = (const float*)d_in[3];
    const float* wo     = (const float*)d_in[4];
    const float* h0     = (const float*)d_in[5];
    float* out = (float*)d_out;

    float* h_table = (float*)d_ws;                       // 4096*16 f32   (256 KB)
    float* partial = h_table + NROWS * HID;              // 50*4096 f32   (800 KB)
    short* a_frag  = (short*)(partial + NSLOTS * NROWS); // 256*64*8 bf16 (256 KB)
    short* b_frag  = a_frag + NRB * 64 * 8;              // 2000*64*8 bf16 (2 MB)

    k_prep<<<HT_BLOCKS + WP_BLOCKS, 256, 0, stream>>>(idx, lookup, wx, wh, h0, wo,
                                                      h_table, a_frag, b_frag);
    k_expsum<<<(NRG * XSTRIPS) / 4, 256, 0, stream>>>(a_frag, b_frag, partial);
    k_write<<<STRIPS * CHUNKS, 256, 0, stream>>>(h_table, wo, partial, out);
}